// Round 7
// baseline (649.715 us; speedup 1.0000x reference)
//
#include <hip/hip_runtime.h>
#include <math.h>

// PLDA pairwise scorer, eigendecomposition-free, all-symmetric formulation.
// Y ~= S_wn^{-1/2} (NS sqrt), M = Y*SB*Y (symmetric), F = f0(inv_s*M) via
// degree-24 bivariate Chebyshev (T_k(T5(X))*T_r(X), k,r<=4),
// B = (63/64)*inv_s*Y*F*Y.  out = 2 v_i^T B v_j - q_i - q_j - log_div.
// The whole fit runs as ONE 1024-thread block on ONE CU: dependent phases
// separated by __syncthreads(), data stays L2-hot on a single XCD (no
// cross-XCD coherence traffic, no grid barriers, no kernel-launch tax).

#define D 128
#define NCLS 256
#define NPC 64
#define MTEST 8192
#define COUNT (NCLS*NPC)

// ws float-offset layout (disjoint; U/V are 524288 fl each)
#define fMC    0                      // McT bf16 [128][256] = 16384 fl slots
#define fMEAN  16384                  // 128 f32
#define fSCAL  16640                  // scalars (256 f32)
#define fMAT   32768                  // 24 dual-plane matrices x 16384 fl
#define fSWRAW (fMAT + 21*16384)      // slot 21: 16384 f32 Gram sum
#define fPART  425984                 // 64*16384 f32 partials (dead after k_reduce)
#define fU     425984                 // 524288 fl -> ends 950272
#define fV     950272                 // 524288 fl -> ends 1474560
#define fQ     1474560                // 8192 fl
#define fBBF   1482752                // 8192 fl (16384 ushort)

using short8 = __attribute__((ext_vector_type(8))) short;
using f32x4  = __attribute__((ext_vector_type(4))) float;

__device__ inline unsigned short f2bf(float f) {
  unsigned u = __float_as_uint(f);
  unsigned r = u + 0x7FFFu + ((u >> 16) & 1u);
  return (unsigned short)(r >> 16);
}
__device__ inline float bf2f(unsigned short h) {
  return __uint_as_float(((unsigned)h) << 16);
}
__device__ inline float valU(const unsigned short* m, int idx) {
  return bf2f(m[idx]) + bf2f(m[idx + 16384]);
}
__device__ inline void storeDual(unsigned short* m, int idx, float g) {
  unsigned short hb = f2bf(g);
  m[idx] = hb;
  m[16384 + idx] = f2bf(g - bf2f(hb));
}

// ---------------- K1: Gram partials over 256-row chunks + class means ----------------
__global__ __launch_bounds__(256) void k_gt_partial(const float* __restrict__ X, float* __restrict__ ws) {
  __shared__ unsigned short xt[128 * 256]; // 64 KB, [d][s] swizzled
  int b = blockIdx.x, tid = threadIdx.x;
  const float* Xc = X + b * 256 * D;
  for (int idx = tid; idx < 256 * D; idx += 256) {
    int s = idx >> 7, d = idx & 127;
    unsigned byte = ((unsigned)(d * 512 + s * 2)) ^ (((unsigned)(d & 7)) << 4);
    *(unsigned short*)((char*)xt + byte) = f2bf(Xc[idx]);
  }
  // class means for classes 4b..4b+3 (f32 accumulate from global X)
  {
    int d = tid & 127;
    for (int cc = (tid >> 7); cc < 4; cc += 2) {
      const float* p = Xc + cc * 64 * D + d;
      float s = 0.f;
      #pragma unroll
      for (int n = 0; n < 64; n++) s += p[n * D];
      ((unsigned short*)ws)[d * 256 + (b * 4 + cc)] = f2bf(s * (1.0f / 64.0f));
    }
  }
  __syncthreads();
  int w = tid >> 6, lane = tid & 63;
  int wr = (w >> 1) * 64, wc = (w & 1) * 64;
  f32x4 acc[4][4] = {};
  for (int ks = 0; ks < 8; ks++) {
    int kb = ks * 32 + (lane >> 4) * 8;
    short8 af[4];
    #pragma unroll
    for (int mt = 0; mt < 4; mt++) {
      int r = wr + mt * 16 + (lane & 15);
      unsigned byte = ((unsigned)(r * 512 + kb * 2)) ^ (((unsigned)(r & 7)) << 4);
      af[mt] = *(short8*)((char*)xt + byte);
    }
    #pragma unroll
    for (int nt = 0; nt < 4; nt++) {
      int c = wc + nt * 16 + (lane & 15);
      unsigned byte = ((unsigned)(c * 512 + kb * 2)) ^ (((unsigned)(c & 7)) << 4);
      short8 bfr = *(short8*)((char*)xt + byte);
      #pragma unroll
      for (int mt = 0; mt < 4; mt++)
        acc[mt][nt] = __builtin_amdgcn_mfma_f32_16x16x32_bf16(af[mt], bfr, acc[mt][nt], 0, 0, 0);
    }
  }
  float* outp = ws + fPART + b * 16384;
  #pragma unroll
  for (int mt = 0; mt < 4; mt++)
    #pragma unroll
    for (int nt = 0; nt < 4; nt++)
      #pragma unroll
      for (int r = 0; r < 4; r++) {
        int row = wr + mt * 16 + (lane >> 4) * 4 + r;
        int col = wc + nt * 16 + (lane & 15);
        outp[row * 128 + col] = acc[mt][nt][r];
      }
}

// ---------------- K2: reduce Gram partials; block0: global mean ----------------
__global__ void k_reduce(float* __restrict__ ws) {
  int tid = threadIdx.x;
  int idx = blockIdx.x * 256 + tid;
  const float* part = ws + fPART;
  float s = 0.f;
  #pragma unroll 8
  for (int p = 0; p < 64; p++) s += part[p * 16384 + idx];
  ws[fSWRAW + idx] = s;
  if (blockIdx.x == 0 && tid < 128) {
    const unsigned short* McT = (const unsigned short*)ws;
    float m = 0.f;
    for (int k = 0; k < 256; k++) m += bf2f(McT[tid * 256 + k]);
    ws[fMEAN + tid] = m * (1.0f / 256.0f);
  }
}

// ---------------- dual-bf16 128^3 matmul phase, 16 waves, symmetric B ----------------
// C = alpha*(*alpha_ptr)*(A*B) + beta*E1 + gamma*E2 + delta*I ; opt ||C||_F^2 -> scal[slot]
__device__ __forceinline__ void mm_phase(
    const unsigned short* A, const unsigned short* B, unsigned short* C,
    const unsigned short* E1, const unsigned short* E2,
    float alpha, const float* alpha_ptr, float beta, float gamma, float delta,
    float* scal, int trace_slot, float* red) {
  int tid = threadIdx.x;
  int w = tid >> 6, lane = tid & 63;
  int brow = (w >> 2) * 32, wcol = (w & 3) * 32;
  f32x4 acc[2][2] = {};
  #pragma unroll
  for (int ks = 0; ks < 4; ks++) {
    int kb = ks * 32 + (lane >> 4) * 8;
    short8 ah[2], al[2], bh[2], bl[2];
    #pragma unroll
    for (int mt = 0; mt < 2; mt++) {
      int r = brow + mt * 16 + (lane & 15);
      ah[mt] = *(const short8*)(A + r * 128 + kb);
      al[mt] = *(const short8*)(A + 16384 + r * 128 + kb);
    }
    #pragma unroll
    for (int nt = 0; nt < 2; nt++) {
      int c = wcol + nt * 16 + (lane & 15);
      bh[nt] = *(const short8*)(B + c * 128 + kb);      // symmetric: row c == col c
      bl[nt] = *(const short8*)(B + 16384 + c * 128 + kb);
    }
    #pragma unroll
    for (int mt = 0; mt < 2; mt++)
      #pragma unroll
      for (int nt = 0; nt < 2; nt++) {
        f32x4 a0 = acc[mt][nt];
        a0 = __builtin_amdgcn_mfma_f32_16x16x32_bf16(ah[mt], bh[nt], a0, 0, 0, 0);
        a0 = __builtin_amdgcn_mfma_f32_16x16x32_bf16(al[mt], bh[nt], a0, 0, 0, 0);
        a0 = __builtin_amdgcn_mfma_f32_16x16x32_bf16(ah[mt], bl[nt], a0, 0, 0, 0);
        acc[mt][nt] = a0;
      }
  }
  float aeff = alpha * (alpha_ptr ? alpha_ptr[0] : 1.0f);
  float tsum = 0.0f;
  #pragma unroll
  for (int mt = 0; mt < 2; mt++)
    #pragma unroll
    for (int nt = 0; nt < 2; nt++)
      #pragma unroll
      for (int r = 0; r < 4; r++) {
        int row = brow + mt * 16 + (lane >> 4) * 4 + r;
        int col = wcol + nt * 16 + (lane & 15);
        int idx = row * 128 + col;
        float g = acc[mt][nt][r] * aeff;
        if (E1) g += beta * (bf2f(E1[idx]) + bf2f(E1[16384 + idx]));
        if (E2) g += gamma * (bf2f(E2[idx]) + bf2f(E2[16384 + idx]));
        if (row == col) g += delta;
        storeDual(C, idx, g);
        tsum += g * g;
      }
  if (trace_slot >= 0) {
    #pragma unroll
    for (int off = 32; off > 0; off >>= 1) tsum += __shfl_down(tsum, off);
    if (lane == 0) red[w] = tsum;
    __syncthreads();
    if (tid == 0) {
      float s = 0.f;
      #pragma unroll
      for (int i = 0; i < 16; i++) s += red[i];
      scal[trace_slot] = s;
    }
  }
}

// ---------------- K3: the whole fit, ONE block x 1024 threads ----------------
__global__ __launch_bounds__(1024) void k_fit_1blk(float* __restrict__ ws) {
  __shared__ float red[16];
  __shared__ float cs[8];     // th, x0, SCc, c0, ih
  __shared__ float sat[25];   // Chebyshev at[]
  __shared__ float sc[25];    // bivariate c[k][r]
  float* scal = ws + fSCAL;
  const float* mv = ws + fMEAN;
  unsigned short* MATB = (unsigned short*)(ws + fMAT);
  unsigned short *SW = MATB, *SB = MATB + 1*32768, *Y1 = MATB + 2*32768,
    *Wt = MATB + 3*32768, *Qt = MATB + 4*32768, *Y2 = MATB + 5*32768,
    *Y3 = MATB + 6*32768, *M1 = MATB + 7*32768, *Mm = MATB + 8*32768,
    *C2 = MATB + 9*32768, *XH = MATB + 11*32768,
    *T2 = MATB + 12*32768, *T3 = MATB + 13*32768, *T4 = MATB + 14*32768,
    *Y5 = MATB + 15*32768, *G0 = MATB + 16*32768, *G1 = MATB + 17*32768,
    *G2 = MATB + 18*32768, *G3 = MATB + 19*32768, *G4 = MATB + 20*32768,
    *C4 = MATB + 10*32768, *B3 = MATB + 10*32768, *B2 = MATB + 22*32768,
    *B1 = MATB + 23*32768, *Fm = MATB + 3*32768, *A1 = MATB + 4*32768,
    *Bq = MATB + 7*32768;
  int tid = threadIdx.x;
  #define BAR() __syncthreads()

  // P0: SB = McT McT^T/256 - m m^T (K=256); tr(S_w) -> inv_s = scal[1]
  {
    const unsigned short* Mc = (const unsigned short*)ws;
    const float* swraw = ws + fSWRAW;
    int w = tid >> 6, lane = tid & 63;
    int brow = (w >> 2) * 32, wcol = (w & 3) * 32;
    f32x4 acc[2][2] = {};
    for (int ks = 0; ks < 8; ks++) {
      int kb = ks * 32 + (lane >> 4) * 8;
      short8 af[2], bfv[2];
      #pragma unroll
      for (int mt = 0; mt < 2; mt++) {
        int r = brow + mt * 16 + (lane & 15);
        af[mt] = *(const short8*)(Mc + r * 256 + kb);
      }
      #pragma unroll
      for (int nt = 0; nt < 2; nt++) {
        int c = wcol + nt * 16 + (lane & 15);
        bfv[nt] = *(const short8*)(Mc + c * 256 + kb);
      }
      #pragma unroll
      for (int mt = 0; mt < 2; mt++)
        #pragma unroll
        for (int nt = 0; nt < 2; nt++)
          acc[mt][nt] = __builtin_amdgcn_mfma_f32_16x16x32_bf16(af[mt], bfv[nt], acc[mt][nt], 0, 0, 0);
    }
    float tsum = 0.f;
    #pragma unroll
    for (int mt = 0; mt < 2; mt++)
      #pragma unroll
      for (int nt = 0; nt < 2; nt++)
        #pragma unroll
        for (int r = 0; r < 4; r++) {
          int row = brow + mt * 16 + (lane >> 4) * 4 + r;
          int col = wcol + nt * 16 + (lane & 15);
          int idx = row * 128 + col;
          float g = acc[mt][nt][r] * (1.0f / 256.0f) - mv[row] * mv[col];
          storeDual(SB, idx, g);
          if (row == col)
            tsum += swraw[row * 129] * (1.0f / COUNT) - g - mv[row] * mv[row];
        }
    #pragma unroll
    for (int off = 32; off > 0; off >>= 1) tsum += __shfl_down(tsum, off);
    if (lane == 0) red[tid >> 6] = tsum;
    __syncthreads();
    if (tid == 0) {
      float tr = 0.f;
      #pragma unroll
      for (int i = 0; i < 16; i++) tr += red[i];
      scal[1] = 128.0f / tr;
    }
  }
  BAR();

  // P1: SW = normalized S_w; Y1 = 1.5I - 0.5 SW
  {
    float inv_s = scal[1];
    const float* swraw = ws + fSWRAW;
    for (int idx = tid; idx < 16384; idx += 1024) {
      int row = idx >> 7, col = idx & 127;
      float sb = valU(SB, idx);
      float s = (swraw[idx] * (1.0f / COUNT) - sb - mv[row] * mv[col]) * inv_s;
      storeDual(SW, idx, s);
      storeDual(Y1, idx, ((row == col) ? 1.5f : 0.0f) - 0.5f * s);
    }
  }
  BAR();

  // Newton-Schulz sqrt (2 iterations)
  mm_phase(Y1, Y1, Wt, nullptr, nullptr, 1.0f, nullptr, 0, 0, 0.0f, scal, -1, red); BAR();
  mm_phase(SW, Wt, Qt, nullptr, nullptr, -1.0f, nullptr, 0, 0, 3.0f, scal, -1, red); BAR();
  mm_phase(Y1, Qt, Y2, nullptr, nullptr, 0.5f, nullptr, 0, 0, 0.0f, scal, -1, red); BAR();
  mm_phase(Y2, Y2, Wt, nullptr, nullptr, 1.0f, nullptr, 0, 0, 0.0f, scal, -1, red); BAR();
  mm_phase(SW, Wt, Qt, nullptr, nullptr, -1.0f, nullptr, 0, 0, 3.0f, scal, -1, red); BAR();
  mm_phase(Y2, Qt, Y3, nullptr, nullptr, 0.5f, nullptr, 0, 0, 0.0f, scal, -1, red); BAR();
  // M = Y*SB*Y; C2 = M^2; C4 = M^4 (+ tr(M^8) -> scal[68])
  mm_phase(Y3, SB, M1, nullptr, nullptr, 1.0f, nullptr, 0, 0, 0.0f, scal, -1, red); BAR();
  mm_phase(M1, Y3, Mm, nullptr, nullptr, 1.0f, nullptr, 0, 0, 0.0f, scal, -1, red); BAR();
  mm_phase(Mm, Mm, C2, nullptr, nullptr, 1.0f, nullptr, 0, 0, 0.0f, scal, -1, red); BAR();
  mm_phase(C2, C2, C4, nullptr, nullptr, 1.0f, nullptr, 0, 0, 0.0f, scal, 68, red); BAR();

  // P12: interval + Chebyshev coefs + bivariate transform (LDS-resident)
  if (tid == 0) {
    float s8 = scal[68];                 // tr(M^8)
    float inv_s = scal[1];
    float Lam = 1.03f * sqrtf(sqrtf(sqrtf(fmaxf(s8, 1e-37f))));
    float lo = -0.02f * Lam, hi = Lam;
    float c0 = 0.5f * (hi + lo), h = 0.5f * (hi - lo);
    float ih = 1.0f / h;
    float t0 = (1.0f / 63.0f) / inv_s;
    float x0 = fminf(fmaxf((t0 - c0) * ih, -1.0f), 1.0f);
    cs[0] = acosf(x0); cs[1] = x0; cs[2] = 0.984375f * inv_s * h;
    cs[3] = c0; cs[4] = ih;
    scal[7] = 0.984375f * inv_s;         // B final scale
  }
  BAR();
  if (tid <= 24) {
    float th = cs[0], x0 = cs[1], SCc = cs[2];
    const float PI = 3.14159265358979f;
    float v;
    if (tid == 0) v = 0.5f * SCc * (2.0f / PI) * (sinf(th) - x0 * th);
    else if (tid == 1) v = SCc * (2.0f / PI) * (0.5f * th + 0.25f * sinf(2.0f * th) - x0 * sinf(th));
    else {
      float fj = (float)tid;
      v = SCc * (2.0f / PI) *
          (0.5f * (sinf((fj + 1.0f) * th) / (fj + 1.0f) + sinf((fj - 1.0f) * th) / (fj - 1.0f))
           - x0 * sinf(fj * th) / fj);
    }
    sat[tid] = v;       // at[0] already halved
    sc[tid] = 0.f;
  }
  BAR();
  if (tid == 0) {
    for (int j = 24; j >= 5; --j) {
      int k = j / 5, r = j - 5 * k;
      float aj = sat[j];
      if (r == 0) sc[k * 5] += aj;
      else { sc[k * 5 + r] += 2.0f * aj; sat[5 * k - r] -= aj; }
    }
    for (int r = 0; r < 5; r++) sc[r] += sat[r];
  }
  BAR();

  // P13: XH = ih*(M - c0 I); T2 = 2 XH^2 - I (from C2)
  {
    float c0 = cs[3], ih = cs[4];
    float a2 = 2.0f * ih * ih, b2 = -4.0f * c0 * ih * ih, g2 = 2.0f * c0 * c0 * ih * ih - 1.0f;
    for (int idx = tid; idx < 16384; idx += 1024) {
      int row = idx >> 7, col = idx & 127;
      float m = valU(Mm, idx), c2v = valU(C2, idx);
      float dg = (row == col) ? 1.0f : 0.0f;
      storeDual(XH, idx, ih * m - ih * c0 * dg);
      storeDual(T2, idx, a2 * c2v + b2 * m + g2 * dg);
    }
  }
  BAR();

  // T3 = 2 XH T2 - XH; T4 = 2 T2^2 - I (independent -> no barrier between)
  mm_phase(XH, T2, T3, XH, nullptr, 2.0f, nullptr, -1.0f, 0, 0.0f, scal, -1, red);
  mm_phase(T2, T2, T4, nullptr, nullptr, 2.0f, nullptr, 0, 0, -1.0f, scal, -1, red); BAR();
  mm_phase(T2, T3, Y5, XH, nullptr, 2.0f, nullptr, -1.0f, 0, 0.0f, scal, -1, red); BAR();

  // P17: G_k = sum_r sc[k][r] T_r(X)
  {
    for (int idx = tid; idx < 16384; idx += 1024) {
      int row = idx >> 7, col = idx & 127;
      float dg = (row == col) ? 1.0f : 0.0f;
      float x1 = valU(XH, idx), x2 = valU(T2, idx), x3 = valU(T3, idx), x4 = valU(T4, idx);
      #pragma unroll
      for (int k = 0; k < 5; k++) {
        float g = sc[k * 5 + 0] * dg + sc[k * 5 + 1] * x1 + sc[k * 5 + 2] * x2 +
                  sc[k * 5 + 3] * x3 + sc[k * 5 + 4] * x4;
        storeDual(MATB + (16 + k) * 32768, idx, g);
      }
    }
  }
  BAR();

  // Clenshaw in Y5 with matrix coefficients G0..G4
  mm_phase(Y5, G4, B3, G3, nullptr, 2.0f, nullptr, 1.0f, 0, 0.0f, scal, -1, red); BAR();
  mm_phase(Y5, B3, B2, G4, G2, 2.0f, nullptr, -1.0f, 1.0f, 0.0f, scal, -1, red); BAR();
  mm_phase(Y5, B2, B1, B3, G1, 2.0f, nullptr, -1.0f, 1.0f, 0.0f, scal, -1, red); BAR();
  mm_phase(Y5, B1, Fm, B2, G0, 1.0f, nullptr, -1.0f, 1.0f, 0.0f, scal, 72, red); BAR();
  // B = (63/64)*inv_s * Y*F*Y
  mm_phase(Y3, Fm, A1, nullptr, nullptr, 1.0f, nullptr, 0, 0, 0.0f, scal, -1, red); BAR();
  mm_phase(A1, Y3, Bq, nullptr, nullptr, 1.0f, scal + 7, 0, 0, 0.0f, scal, -1, red); BAR();

  // P24: symmetrize -> single bf16; log_div
  {
    unsigned short* Bbf = (unsigned short*)(ws + fBBF);
    for (int idx = tid; idx < 16384; idx += 1024) {
      int r = idx >> 7, c = idx & 127;
      Bbf[idx] = f2bf(0.5f * (valU(Bq, idx) + valU(Bq, c * 128 + r)));
    }
    if (tid == 0) {
      float trF2 = fmaxf(scal[72], 1e-30f);
      scal[0] = 0.5f * (128.0f * 1.8378770664093453f + 0.5f * logf(trF2));
    }
  }
  #undef BAR
}

// ---------------- K4: V = test - mean (bf16); U = V*B; q_i = U_i.V_i ----------------
__global__ __launch_bounds__(256) void k_latent(const float* __restrict__ test, float* __restrict__ ws) {
  __shared__ unsigned short vh[16384];
  __shared__ float qs[128];
  int blk = blockIdx.x, tid = threadIdx.x;
  const float* tb = test + blk * 128 * D;
  unsigned short* Vbf = (unsigned short*)(ws + fV);
  if (tid < 128) qs[tid] = 0.f;
  for (int idx = tid; idx < 16384; idx += 256) {
    int r = idx >> 7, c = idx & 127;
    float v = tb[idx] - ws[fMEAN + c];
    unsigned short h = f2bf(v);
    unsigned byte = ((unsigned)(r * 256 + c * 2)) ^ (((unsigned)(r & 7)) << 4);
    *(unsigned short*)((char*)vh + byte) = h;
    Vbf[blk * 16384 + idx] = h;
  }
  __syncthreads();
  int w = tid >> 6, lane = tid & 63;
  int wr = (w >> 1) * 64, wc = (w & 1) * 64;
  const unsigned short* Bbf = (const unsigned short*)(ws + fBBF);
  f32x4 acc[4][4] = {};
  for (int ks = 0; ks < 4; ks++) {
    int kb = ks * 32 + (lane >> 4) * 8;
    short8 af[4], bfv[4];
    #pragma unroll
    for (int mt = 0; mt < 4; mt++) {
      int r = wr + mt * 16 + (lane & 15);
      unsigned byte = ((unsigned)(r * 256 + kb * 2)) ^ (((unsigned)(r & 7)) << 4);
      af[mt] = *(short8*)((char*)vh + byte);
    }
    #pragma unroll
    for (int nt = 0; nt < 4; nt++) {
      int c = wc + nt * 16 + (lane & 15);
      bfv[nt] = *(const short8*)(Bbf + c * 128 + kb); // B symmetric
    }
    #pragma unroll
    for (int mt = 0; mt < 4; mt++)
      #pragma unroll
      for (int nt = 0; nt < 4; nt++)
        acc[mt][nt] = __builtin_amdgcn_mfma_f32_16x16x32_bf16(af[mt], bfv[nt], acc[mt][nt], 0, 0, 0);
  }
  unsigned short* Ubf = (unsigned short*)(ws + fU);
  #pragma unroll
  for (int mt = 0; mt < 4; mt++)
    #pragma unroll
    for (int nt = 0; nt < 4; nt++)
      #pragma unroll
      for (int r = 0; r < 4; r++) {
        int row = wr + mt * 16 + (lane >> 4) * 4 + r;
        int col = wc + nt * 16 + (lane & 15);
        Ubf[(blk * 128 + row) * 128 + col] = f2bf(acc[mt][nt][r]);
      }
  // fused q: per-row dot of (bf16-rounded U) with V
  #pragma unroll
  for (int mt = 0; mt < 4; mt++)
    #pragma unroll
    for (int r = 0; r < 4; r++) {
      int row = wr + mt * 16 + (lane >> 4) * 4 + r;
      float p = 0.f;
      #pragma unroll
      for (int nt = 0; nt < 4; nt++) {
        int col = wc + nt * 16 + (lane & 15);
        unsigned byte = ((unsigned)(row * 256 + col * 2)) ^ (((unsigned)(row & 7)) << 4);
        p += bf2f(f2bf(acc[mt][nt][r])) * bf2f(*(unsigned short*)((char*)vh + byte));
      }
      p += __shfl_xor(p, 1, 16);
      p += __shfl_xor(p, 2, 16);
      p += __shfl_xor(p, 4, 16);
      p += __shfl_xor(p, 8, 16);
      if ((lane & 15) == 0) atomicAdd(&qs[row], p);  // exactly 2 adds/row: deterministic
    }
  __syncthreads();
  if (tid < 128) ws[fQ + blk * 128 + tid] = qs[tid];
}

// ---------------- K5: out = 2 U V^T - q_i - q_j - log_div ----------------
__global__ __launch_bounds__(256) void k_pair(const float* __restrict__ ws, float* __restrict__ out) {
  __shared__ float qi[128];
  __shared__ float qj[128];
  __shared__ float sld;
  int bi = blockIdx.x, bj = blockIdx.y, tid = threadIdx.x;
  if (tid < 128) qi[tid] = ws[fQ + bi * 128 + tid];
  else qj[tid - 128] = ws[fQ + bj * 128 + (tid - 128)];
  if (tid == 0) sld = ws[fSCAL + 0];
  __syncthreads();
  int w = tid >> 6, lane = tid & 63;
  int wr = (w >> 1) * 64, wc = (w & 1) * 64;
  const unsigned short* Ubf = (const unsigned short*)(ws + fU);
  const unsigned short* Vbf = (const unsigned short*)(ws + fV);
  f32x4 acc[4][4] = {};
  for (int ks = 0; ks < 4; ks++) {
    int kb = ks * 32 + (lane >> 4) * 8;
    short8 af[4], bfv[4];
    #pragma unroll
    for (int mt = 0; mt < 4; mt++) {
      int r = bi * 128 + wr + mt * 16 + (lane & 15);
      af[mt] = *(const short8*)(Ubf + r * 128 + kb);
    }
    #pragma unroll
    for (int nt = 0; nt < 4; nt++) {
      int c = bj * 128 + wc + nt * 16 + (lane & 15);
      bfv[nt] = *(const short8*)(Vbf + c * 128 + kb);
    }
    #pragma unroll
    for (int mt = 0; mt < 4; mt++)
      #pragma unroll
      for (int nt = 0; nt < 4; nt++)
        acc[mt][nt] = __builtin_amdgcn_mfma_f32_16x16x32_bf16(af[mt], bfv[nt], acc[mt][nt], 0, 0, 0);
  }
  float ld = sld;
  #pragma unroll
  for (int mt = 0; mt < 4; mt++)
    #pragma unroll
    for (int nt = 0; nt < 4; nt++)
      #pragma unroll
      for (int r = 0; r < 4; r++) {
        int row = wr + mt * 16 + (lane >> 4) * 4 + r;
        int col = wc + nt * 16 + (lane & 15);
        float g = acc[mt][nt][r];
        out[(size_t)(bi * 128 + row) * MTEST + (bj * 128 + col)] =
          2.0f * g - qi[row] - qj[col] - ld;
      }
}

extern "C" void kernel_launch(void* const* d_in, const int* in_sizes, int n_in,
                              void* d_out, int out_size, void* d_ws, size_t ws_size,
                              hipStream_t stream) {
  (void)in_sizes; (void)n_in; (void)out_size; (void)ws_size;
  const float* X = (const float*)d_in[0];
  const float* test = (const float*)d_in[1];
  float* out = (float*)d_out;
  float* ws = (float*)d_ws;

  k_gt_partial<<<64, 256, 0, stream>>>(X, ws);   // Gram partials + class means
  k_reduce<<<64, 256, 0, stream>>>(ws);          // Gram sum + global mean
  k_fit_1blk<<<1, 1024, 0, stream>>>(ws);        // entire fit on one CU
  k_latent<<<64, 256, 0, stream>>>(test, ws);    // V, U, q
  k_pair<<<dim3(64, 64), 256, 0, stream>>>(ws, out);
}

// Round 8
// 277.777 us; speedup vs baseline: 2.3390x; 2.3390x over previous
//
#include <hip/hip_runtime.h>
#include <math.h>

// PLDA pairwise scorer, eigendecomposition-free, all-symmetric formulation.
// Z = S_wn^{-1/2} via degree-6 Chebyshev poly in P = S_wn - I (runtime-adaptive
// interval from tr P^8).  M = Z*SB*Z, F = f0(inv_s*M) via degree-24 bivariate
// Chebyshev evaluated as F = G0 + T5*G1 + T10*G2 + T15*G3 + T20*G4.
// B = (63/64)*inv_s*Z*F*Z.  out = 2 v_i^T B v_j - q_i - q_j - log_div.
// Multi-launch chain (17 fit launches); every matmul B-operand symmetric.

#define D 128
#define NCLS 256
#define NPC 64
#define MTEST 8192
#define COUNT (NCLS*NPC)

// ws float-offset layout
#define fMC    0                      // McT bf16 [128][256] = 16384 fl slots
#define fMEAN  16384                  // 128 f32
#define fSCAL  16640                  // scalars (256 f32)
#define fMAT   32768                  // 25 dual-plane matrices x 16384 fl
#define fSWRAW 442368                 // 16384 f32 Gram sum
#define fPART  458752                 // 64*16384 f32 (dead after k_reduce)
#define fU     458752                 // 524288 fl -> ends 983040
#define fV     983040                 // 524288 fl -> ends 1507328
#define fQ     1507328                // 8192 fl
#define fBBF   1515520                // 8192 fl (16384 ushort) -> ends 1523712

// matrix slots
#define sP   0
#define sSB  1
#define sP2  2
#define sP3  3
#define sP4  4
#define sZ   5
#define sM1  6
#define sMm  7
#define sC2  8
#define sC4  9
#define sXH  10
#define sT2  11
#define sT3  12
#define sT4  13
#define sT5  14
#define sT10 15
#define sT15 16
#define sT20 17
#define sG0  18   // G0..G4 = 18..22
#define sF   23
#define sA1  24

using short8 = __attribute__((ext_vector_type(8))) short;
using f32x4  = __attribute__((ext_vector_type(4))) float;

__device__ inline unsigned short f2bf(float f) {
  unsigned u = __float_as_uint(f);
  unsigned r = u + 0x7FFFu + ((u >> 16) & 1u);
  return (unsigned short)(r >> 16);
}
__device__ inline float bf2f(unsigned short h) {
  return __uint_as_float(((unsigned)h) << 16);
}
__device__ inline float valU(const unsigned short* m, int idx) {
  return bf2f(m[idx]) + bf2f(m[idx + 16384]);
}
__device__ inline void storeDual(unsigned short* m, int idx, float g) {
  unsigned short hb = f2bf(g);
  m[idx] = hb;
  m[16384 + idx] = f2bf(g - bf2f(hb));
}
__device__ inline unsigned short* MS(float* ws, int m) {
  return (unsigned short*)(ws + fMAT) + (size_t)m * 32768;
}
__device__ inline const unsigned short* MSc(const float* ws, int m) {
  return (const unsigned short*)(ws + fMAT) + (size_t)m * 32768;
}

// ---------------- K1: Gram partials over 256-row chunks + class means ----------------
__global__ __launch_bounds__(256) void k_gt_partial(const float* __restrict__ X, float* __restrict__ ws) {
  __shared__ unsigned short xt[128 * 256]; // 64 KB, [d][s] swizzled
  int b = blockIdx.x, tid = threadIdx.x;
  const float* Xc = X + b * 256 * D;
  for (int idx = tid; idx < 256 * D; idx += 256) {
    int s = idx >> 7, d = idx & 127;
    unsigned byte = ((unsigned)(d * 512 + s * 2)) ^ (((unsigned)(d & 7)) << 4);
    *(unsigned short*)((char*)xt + byte) = f2bf(Xc[idx]);
  }
  {
    int d = tid & 127;
    for (int cc = (tid >> 7); cc < 4; cc += 2) {
      const float* p = Xc + cc * 64 * D + d;
      float s = 0.f;
      #pragma unroll
      for (int n = 0; n < 64; n++) s += p[n * D];
      ((unsigned short*)ws)[d * 256 + (b * 4 + cc)] = f2bf(s * (1.0f / 64.0f));
    }
  }
  __syncthreads();
  int w = tid >> 6, lane = tid & 63;
  int wr = (w >> 1) * 64, wc = (w & 1) * 64;
  f32x4 acc[4][4] = {};
  for (int ks = 0; ks < 8; ks++) {
    int kb = ks * 32 + (lane >> 4) * 8;
    short8 af[4];
    #pragma unroll
    for (int mt = 0; mt < 4; mt++) {
      int r = wr + mt * 16 + (lane & 15);
      unsigned byte = ((unsigned)(r * 512 + kb * 2)) ^ (((unsigned)(r & 7)) << 4);
      af[mt] = *(short8*)((char*)xt + byte);
    }
    #pragma unroll
    for (int nt = 0; nt < 4; nt++) {
      int c = wc + nt * 16 + (lane & 15);
      unsigned byte = ((unsigned)(c * 512 + kb * 2)) ^ (((unsigned)(c & 7)) << 4);
      short8 bfr = *(short8*)((char*)xt + byte);
      #pragma unroll
      for (int mt = 0; mt < 4; mt++)
        acc[mt][nt] = __builtin_amdgcn_mfma_f32_16x16x32_bf16(af[mt], bfr, acc[mt][nt], 0, 0, 0);
    }
  }
  float* outp = ws + fPART + b * 16384;
  #pragma unroll
  for (int mt = 0; mt < 4; mt++)
    #pragma unroll
    for (int nt = 0; nt < 4; nt++)
      #pragma unroll
      for (int r = 0; r < 4; r++) {
        int row = wr + mt * 16 + (lane >> 4) * 4 + r;
        int col = wc + nt * 16 + (lane & 15);
        outp[row * 128 + col] = acc[mt][nt][r];
      }
}

// ---------------- K2: reduce Gram partials; block0: global mean ----------------
__global__ void k_reduce(float* __restrict__ ws) {
  int tid = threadIdx.x;
  int idx = blockIdx.x * 256 + tid;
  const float* part = ws + fPART;
  float s = 0.f;
  #pragma unroll 8
  for (int p = 0; p < 64; p++) s += part[p * 16384 + idx];
  ws[fSWRAW + idx] = s;
  if (blockIdx.x == 0 && tid < 128) {
    const unsigned short* McT = (const unsigned short*)ws;
    float m = 0.f;
    for (int k = 0; k < 256; k++) m += bf2f(McT[tid * 256 + k]);
    ws[fMEAN + tid] = m * (1.0f / 256.0f);
  }
}

// ---------------- K3: SB = McT McT^T/256 - m m^T; S_w trace partials ----------------
__global__ __launch_bounds__(256) void k_sb(float* __restrict__ ws) {
  __shared__ float red[4];
  const unsigned short* Mc = (const unsigned short*)ws;
  const float* mv = ws + fMEAN;
  const float* swraw = ws + fSWRAW;
  unsigned short* SB = MS(ws, sSB);
  float* scal = ws + fSCAL;
  int tid = threadIdx.x, b = blockIdx.x;
  int w = tid >> 6, lane = tid & 63;
  int brow = b * 32, wcol = w * 32;
  f32x4 acc[2][2] = {};
  for (int ks = 0; ks < 8; ks++) {
    int kb = ks * 32 + (lane >> 4) * 8;
    short8 af[2], bfv[2];
    #pragma unroll
    for (int mt = 0; mt < 2; mt++) {
      int r = brow + mt * 16 + (lane & 15);
      af[mt] = *(const short8*)(Mc + r * 256 + kb);
    }
    #pragma unroll
    for (int nt = 0; nt < 2; nt++) {
      int c = wcol + nt * 16 + (lane & 15);
      bfv[nt] = *(const short8*)(Mc + c * 256 + kb);
    }
    #pragma unroll
    for (int mt = 0; mt < 2; mt++)
      #pragma unroll
      for (int nt = 0; nt < 2; nt++)
        acc[mt][nt] = __builtin_amdgcn_mfma_f32_16x16x32_bf16(af[mt], bfv[nt], acc[mt][nt], 0, 0, 0);
  }
  float tsum = 0.f;
  #pragma unroll
  for (int mt = 0; mt < 2; mt++)
    #pragma unroll
    for (int nt = 0; nt < 2; nt++)
      #pragma unroll
      for (int r = 0; r < 4; r++) {
        int row = brow + mt * 16 + (lane >> 4) * 4 + r;
        int col = wcol + nt * 16 + (lane & 15);
        int idx = row * 128 + col;
        float g = acc[mt][nt][r] * (1.0f / 256.0f) - mv[row] * mv[col];
        storeDual(SB, idx, g);
        if (row == col)
          tsum += swraw[row * 129] * (1.0f / COUNT) - g - mv[row] * mv[row];
      }
  #pragma unroll
  for (int off = 32; off > 0; off >>= 1) tsum += __shfl_down(tsum, off);
  if (lane == 0) red[w] = tsum;
  __syncthreads();
  if (tid == 0) scal[64 + b] = red[0] + red[1] + red[2] + red[3];
}

// ---------------- K4: P = S_wn - I (dual); scal[1],scal[7] ----------------
__global__ __launch_bounds__(256) void k_swfin(float* __restrict__ ws) {
  float* scal = ws + fSCAL;
  float inv_s = 128.0f / (scal[64] + scal[65] + scal[66] + scal[67]);
  const float* mv = ws + fMEAN;
  const float* swraw = ws + fSWRAW;
  const unsigned short* SB = MS(ws, sSB);
  unsigned short* P = MS(ws, sP);
  int gid = blockIdx.x * 256 + threadIdx.x;
  #pragma unroll
  for (int t = 0; t < 4; t++) {
    int idx = gid * 4 + t;
    int row = idx >> 7, col = idx & 127;
    float sb = valU(SB, idx);
    float s = (swraw[idx] * (1.0f / COUNT) - sb - mv[row] * mv[col]) * inv_s;
    storeDual(P, idx, s - ((row == col) ? 1.0f : 0.0f));
  }
  if (blockIdx.x == 0 && threadIdx.x == 0) {
    scal[1] = inv_s;
    scal[7] = 0.984375f * inv_s;
  }
}

// ---------------- generic matmul body: C = a*(A*B) + beta*E1 + delta*I ----------------
__device__ __forceinline__ void mm_body(
    const unsigned short* __restrict__ A, const unsigned short* __restrict__ B,
    unsigned short* __restrict__ C, const unsigned short* __restrict__ E1,
    float alpha, const float* alpha_ptr, float beta, float delta,
    float* scal, int trace_slot, unsigned short* outBf, int b, float* red) {
  int tid = threadIdx.x;
  int w = tid >> 6, lane = tid & 63;
  int brow = b * 32, wcol = w * 32;
  f32x4 acc[2][2] = {};
  #pragma unroll
  for (int ks = 0; ks < 4; ks++) {
    int kb = ks * 32 + (lane >> 4) * 8;
    short8 ah[2], al[2], bh[2], bl[2];
    #pragma unroll
    for (int mt = 0; mt < 2; mt++) {
      int r = brow + mt * 16 + (lane & 15);
      ah[mt] = *(const short8*)(A + r * 128 + kb);
      al[mt] = *(const short8*)(A + 16384 + r * 128 + kb);
    }
    #pragma unroll
    for (int nt = 0; nt < 2; nt++) {
      int c = wcol + nt * 16 + (lane & 15);
      bh[nt] = *(const short8*)(B + c * 128 + kb);      // symmetric B
      bl[nt] = *(const short8*)(B + 16384 + c * 128 + kb);
    }
    #pragma unroll
    for (int mt = 0; mt < 2; mt++)
      #pragma unroll
      for (int nt = 0; nt < 2; nt++) {
        f32x4 a0 = acc[mt][nt];
        a0 = __builtin_amdgcn_mfma_f32_16x16x32_bf16(ah[mt], bh[nt], a0, 0, 0, 0);
        a0 = __builtin_amdgcn_mfma_f32_16x16x32_bf16(al[mt], bh[nt], a0, 0, 0, 0);
        a0 = __builtin_amdgcn_mfma_f32_16x16x32_bf16(ah[mt], bl[nt], a0, 0, 0, 0);
        acc[mt][nt] = a0;
      }
  }
  float aeff = alpha * (alpha_ptr ? alpha_ptr[0] : 1.0f);
  float tsum = 0.0f;
  #pragma unroll
  for (int mt = 0; mt < 2; mt++)
    #pragma unroll
    for (int nt = 0; nt < 2; nt++)
      #pragma unroll
      for (int r = 0; r < 4; r++) {
        int row = brow + mt * 16 + (lane >> 4) * 4 + r;
        int col = wcol + nt * 16 + (lane & 15);
        int idx = row * 128 + col;
        float g = acc[mt][nt][r] * aeff;
        if (E1) g += beta * (bf2f(E1[idx]) + bf2f(E1[16384 + idx]));
        if (row == col) g += delta;
        if (outBf) outBf[idx] = f2bf(g);
        else storeDual(C, idx, g);
        tsum += g * g;
      }
  if (trace_slot >= 0) {
    #pragma unroll
    for (int off = 32; off > 0; off >>= 1) tsum += __shfl_down(tsum, off);
    if (lane == 0) red[w] = tsum;
    __syncthreads();
    if (tid == 0) scal[trace_slot + b] = red[0] + red[1] + red[2] + red[3];
  }
}

__global__ __launch_bounds__(256) void k_mm(
    const unsigned short* A, const unsigned short* B, unsigned short* C,
    const unsigned short* E1, float alpha, const float* alpha_ptr,
    float beta, float delta, float* scal, int trace_slot, unsigned short* outBf) {
  __shared__ float red[4];
  mm_body(A, B, C, E1, alpha, alpha_ptr, beta, delta, scal, trace_slot, outBf, blockIdx.x, red);
}

// two independent products in one launch (blocks 0-3 task0, 4-7 task1; trace on task1)
__global__ __launch_bounds__(256) void k_mm2(
    const unsigned short* A0, const unsigned short* B0, unsigned short* C0,
    const unsigned short* E0, float al0, float be0, float de0,
    const unsigned short* A1, const unsigned short* B1, unsigned short* C1,
    const unsigned short* E1, float al1, float be1, float de1,
    float* scal, int tslot1) {
  __shared__ float red[4];
  int b = blockIdx.x & 3;
  if (blockIdx.x < 4)
    mm_body(A0, B0, C0, E0, al0, nullptr, be0, de0, scal, -1, nullptr, b, red);
  else
    mm_body(A1, B1, C1, E1, al1, nullptr, be1, de1, scal, tslot1, nullptr, b, red);
}

// ---------------- K7: P5,P6 + Z = sum beta_k P^k (beta from inline Chebyshev fit) ----------------
__global__ __launch_bounds__(256) void k_p56z(float* __restrict__ ws) {
  __shared__ float cj[7];
  __shared__ float bt[7];
  float* scal = ws + fSCAL;
  const unsigned short *P = MSc(ws, sP), *P2 = MSc(ws, sP2),
    *P3 = MSc(ws, sP3), *P4 = MSc(ws, sP4);
  unsigned short* Z = MS(ws, sZ);
  int tid = threadIdx.x, b = blockIdx.x;
  float trP8 = scal[60] + scal[61] + scal[62] + scal[63];
  float a = 1.05f * sqrtf(sqrtf(sqrtf(fmaxf(trP8, 1e-30f))));
  a = fminf(a, 0.95f);
  if (tid < 7) {
    const float PI = 3.14159265358979f;
    float s = 0.f;
    for (int i = 0; i < 64; i++) {
      float th = (i + 0.5f) * (PI / 64.0f);
      float x = cosf(th);
      s += (1.0f / sqrtf(1.0f + a * x)) * cosf((float)tid * th);
    }
    cj[tid] = s * (2.0f / 64.0f);
  }
  __syncthreads();
  if (tid == 0) {
    float c0h = 0.5f * cj[0];
    float m0 = c0h - cj[2] + cj[4] - cj[6];
    float m1 = cj[1] - 3.0f * cj[3] + 5.0f * cj[5];
    float m2 = 2.0f * cj[2] - 8.0f * cj[4] + 18.0f * cj[6];
    float m3 = 4.0f * cj[3] - 20.0f * cj[5];
    float m4 = 8.0f * cj[4] - 48.0f * cj[6];
    float m5 = 16.0f * cj[5];
    float m6 = 32.0f * cj[6];
    float ia = 1.0f / a;
    float p = 1.f;
    bt[0] = m0;
    p *= ia; bt[1] = m1 * p;
    p *= ia; bt[2] = m2 * p;
    p *= ia; bt[3] = m3 * p;
    p *= ia; bt[4] = m4 * p;
    p *= ia; bt[5] = m5 * p;
    p *= ia; bt[6] = m6 * p;
  }
  __syncthreads();
  int w = tid >> 6, lane = tid & 63;
  int brow = b * 32, wcol = w * 32;
  f32x4 a5[2][2] = {}, a6[2][2] = {};
  #pragma unroll
  for (int ks = 0; ks < 4; ks++) {
    int kb = ks * 32 + (lane >> 4) * 8;
    short8 ah[2], al[2], b5h[2], b5l[2], b6h[2], b6l[2];
    #pragma unroll
    for (int mt = 0; mt < 2; mt++) {
      int r = brow + mt * 16 + (lane & 15);
      ah[mt] = *(const short8*)(P4 + r * 128 + kb);
      al[mt] = *(const short8*)(P4 + 16384 + r * 128 + kb);
    }
    #pragma unroll
    for (int nt = 0; nt < 2; nt++) {
      int c = wcol + nt * 16 + (lane & 15);
      b5h[nt] = *(const short8*)(P + c * 128 + kb);
      b5l[nt] = *(const short8*)(P + 16384 + c * 128 + kb);
      b6h[nt] = *(const short8*)(P2 + c * 128 + kb);
      b6l[nt] = *(const short8*)(P2 + 16384 + c * 128 + kb);
    }
    #pragma unroll
    for (int mt = 0; mt < 2; mt++)
      #pragma unroll
      for (int nt = 0; nt < 2; nt++) {
        f32x4 x5 = a5[mt][nt];
        x5 = __builtin_amdgcn_mfma_f32_16x16x32_bf16(ah[mt], b5h[nt], x5, 0, 0, 0);
        x5 = __builtin_amdgcn_mfma_f32_16x16x32_bf16(al[mt], b5h[nt], x5, 0, 0, 0);
        x5 = __builtin_amdgcn_mfma_f32_16x16x32_bf16(ah[mt], b5l[nt], x5, 0, 0, 0);
        a5[mt][nt] = x5;
        f32x4 x6 = a6[mt][nt];
        x6 = __builtin_amdgcn_mfma_f32_16x16x32_bf16(ah[mt], b6h[nt], x6, 0, 0, 0);
        x6 = __builtin_amdgcn_mfma_f32_16x16x32_bf16(al[mt], b6h[nt], x6, 0, 0, 0);
        x6 = __builtin_amdgcn_mfma_f32_16x16x32_bf16(ah[mt], b6l[nt], x6, 0, 0, 0);
        a6[mt][nt] = x6;
      }
  }
  #pragma unroll
  for (int mt = 0; mt < 2; mt++)
    #pragma unroll
    for (int nt = 0; nt < 2; nt++)
      #pragma unroll
      for (int r = 0; r < 4; r++) {
        int row = brow + mt * 16 + (lane >> 4) * 4 + r;
        int col = wcol + nt * 16 + (lane & 15);
        int idx = row * 128 + col;
        float dg = (row == col) ? 1.0f : 0.0f;
        float z = bt[0] * dg + bt[1] * valU(P, idx) + bt[2] * valU(P2, idx) +
                  bt[3] * valU(P3, idx) + bt[4] * valU(P4, idx) +
                  bt[5] * a5[mt][nt][r] + bt[6] * a6[mt][nt][r];
        storeDual(Z, idx, z);
      }
}

// interval helper (closed form from scal)
__device__ inline void interval_cs(const float* scal, float* c0o, float* iho) {
  float trM8 = scal[68] + scal[69] + scal[70] + scal[71];
  float Lam = 1.03f * sqrtf(sqrtf(sqrtf(fmaxf(trM8, 1e-37f))));
  float lo = -0.02f * Lam, hi = Lam;
  *c0o = 0.5f * (hi + lo);
  *iho = 1.0f / (0.5f * (hi - lo));
}

// ---------------- K12: XH = ih*(M - c0 I); T2 = 2 XH^2 - I (from C2) ----------------
__global__ __launch_bounds__(256) void k_xh_t2(float* __restrict__ ws) {
  __shared__ float cs[2];
  float* scal = ws + fSCAL;
  if (threadIdx.x == 0) {
    float c0, ih;
    interval_cs(scal, &c0, &ih);
    cs[0] = c0; cs[1] = ih;
  }
  __syncthreads();
  float c0 = cs[0], ih = cs[1];
  float a2 = 2.0f * ih * ih, b2 = -4.0f * c0 * ih * ih, g2 = 2.0f * c0 * c0 * ih * ih - 1.0f;
  const unsigned short* Mm = MSc(ws, sMm);
  const unsigned short* C2 = MSc(ws, sC2);
  unsigned short* XH = MS(ws, sXH);
  unsigned short* T2 = MS(ws, sT2);
  int gid = blockIdx.x * 256 + threadIdx.x;
  #pragma unroll
  for (int t = 0; t < 4; t++) {
    int idx = gid * 4 + t;
    int row = idx >> 7, col = idx & 127;
    float m = valU(Mm, idx), c2v = valU(C2, idx);
    float dg = (row == col) ? 1.0f : 0.0f;
    storeDual(XH, idx, ih * m - ih * c0 * dg);
    storeDual(T2, idx, a2 * c2v + b2 * m + g2 * dg);
  }
}

// ---------------- K14: blocks 0-3: T5 = 2 T2 T3 - XH; blocks 4-19: G0..G4 ----------------
__global__ __launch_bounds__(256) void k_t5g(float* __restrict__ ws) {
  __shared__ float red[4];
  __shared__ float cs[8];
  __shared__ float sat[25];
  __shared__ float sc[25];
  float* scal = ws + fSCAL;
  int tid = threadIdx.x;
  if (blockIdx.x < 4) {
    mm_body(MSc(ws, sT2), MSc(ws, sT3), MS(ws, sT5), MSc(ws, sXH),
            2.0f, nullptr, -1.0f, 0.0f, scal, -1, nullptr, blockIdx.x, red);
    return;
  }
  // gform with inline coef2
  if (tid == 0) {
    float c0, ih;
    interval_cs(scal, &c0, &ih);
    float inv_s = scal[1];
    float t0 = (1.0f / 63.0f) / inv_s;
    float x0 = fminf(fmaxf((t0 - c0) * ih, -1.0f), 1.0f);
    cs[0] = acosf(x0); cs[1] = x0;
    cs[2] = 0.984375f * inv_s / ih;   // SCc = (63/64)*inv_s*h
  }
  __syncthreads();
  if (tid <= 24) {
    float th = cs[0], x0 = cs[1], SCc = cs[2];
    const float PI = 3.14159265358979f;
    float v;
    if (tid == 0) v = 0.5f * SCc * (2.0f / PI) * (sinf(th) - x0 * th);
    else if (tid == 1) v = SCc * (2.0f / PI) * (0.5f * th + 0.25f * sinf(2.0f * th) - x0 * sinf(th));
    else {
      float fj = (float)tid;
      v = SCc * (2.0f / PI) *
          (0.5f * (sinf((fj + 1.0f) * th) / (fj + 1.0f) + sinf((fj - 1.0f) * th) / (fj - 1.0f))
           - x0 * sinf(fj * th) / fj);
    }
    sat[tid] = v;
    sc[tid] = 0.f;
  }
  __syncthreads();
  if (tid == 0) {
    for (int j = 24; j >= 5; --j) {
      int k = j / 5, r = j - 5 * k;
      float aj = sat[j];
      if (r == 0) sc[k * 5] += aj;
      else { sc[k * 5 + r] += 2.0f * aj; sat[5 * k - r] -= aj; }
    }
    for (int r = 0; r < 5; r++) sc[r] += sat[r];
  }
  __syncthreads();
  const unsigned short* XH = MSc(ws, sXH);
  const unsigned short* T2 = MSc(ws, sT2);
  const unsigned short* T3 = MSc(ws, sT3);
  const unsigned short* T4 = MSc(ws, sT4);
  int bg = blockIdx.x - 4;
  int base = bg * 1024 + tid * 4;
  #pragma unroll
  for (int t = 0; t < 4; t++) {
    int idx = base + t;
    int row = idx >> 7, col = idx & 127;
    float dg = (row == col) ? 1.0f : 0.0f;
    float x1 = valU(XH, idx), x2 = valU(T2, idx), x3 = valU(T3, idx), x4 = valU(T4, idx);
    #pragma unroll
    for (int k = 0; k < 5; k++) {
      float g = sc[k * 5 + 0] * dg + sc[k * 5 + 1] * x1 + sc[k * 5 + 2] * x2 +
                sc[k * 5 + 3] * x3 + sc[k * 5 + 4] * x4;
      storeDual(MS(ws, sG0 + k), idx, g);
    }
  }
}

// ---------------- K17: F = G0 + T5 G1 + T10 G2 + T15 G3 + T20 G4 (+trF2) ----------------
__global__ __launch_bounds__(256) void k_bigF(float* __restrict__ ws) {
  __shared__ float red[4];
  float* scal = ws + fSCAL;
  const unsigned short* As[4] = { MSc(ws, sT5), MSc(ws, sT10), MSc(ws, sT15), MSc(ws, sT20) };
  const unsigned short* Bs[4] = { MSc(ws, sG0 + 1), MSc(ws, sG0 + 2), MSc(ws, sG0 + 3), MSc(ws, sG0 + 4) };
  const unsigned short* G0 = MSc(ws, sG0);
  unsigned short* Fm = MS(ws, sF);
  int tid = threadIdx.x, b = blockIdx.x;
  int w = tid >> 6, lane = tid & 63;
  int brow = b * 32, wcol = w * 32;
  f32x4 acc[2][2] = {};
  for (int p = 0; p < 4; p++) {
    const unsigned short* A = As[p];
    const unsigned short* B = Bs[p];
    #pragma unroll
    for (int ks = 0; ks < 4; ks++) {
      int kb = ks * 32 + (lane >> 4) * 8;
      short8 ah[2], al[2], bh[2], bl[2];
      #pragma unroll
      for (int mt = 0; mt < 2; mt++) {
        int r = brow + mt * 16 + (lane & 15);
        ah[mt] = *(const short8*)(A + r * 128 + kb);
        al[mt] = *(const short8*)(A + 16384 + r * 128 + kb);
      }
      #pragma unroll
      for (int nt = 0; nt < 2; nt++) {
        int c = wcol + nt * 16 + (lane & 15);
        bh[nt] = *(const short8*)(B + c * 128 + kb);
        bl[nt] = *(const short8*)(B + 16384 + c * 128 + kb);
      }
      #pragma unroll
      for (int mt = 0; mt < 2; mt++)
        #pragma unroll
        for (int nt = 0; nt < 2; nt++) {
          f32x4 a0 = acc[mt][nt];
          a0 = __builtin_amdgcn_mfma_f32_16x16x32_bf16(ah[mt], bh[nt], a0, 0, 0, 0);
          a0 = __builtin_amdgcn_mfma_f32_16x16x32_bf16(al[mt], bh[nt], a0, 0, 0, 0);
          a0 = __builtin_amdgcn_mfma_f32_16x16x32_bf16(ah[mt], bl[nt], a0, 0, 0, 0);
          acc[mt][nt] = a0;
        }
    }
  }
  float tsum = 0.f;
  #pragma unroll
  for (int mt = 0; mt < 2; mt++)
    #pragma unroll
    for (int nt = 0; nt < 2; nt++)
      #pragma unroll
      for (int r = 0; r < 4; r++) {
        int row = brow + mt * 16 + (lane >> 4) * 4 + r;
        int col = wcol + nt * 16 + (lane & 15);
        int idx = row * 128 + col;
        float g = acc[mt][nt][r] + valU(G0, idx);
        storeDual(Fm, idx, g);
        tsum += g * g;
      }
  #pragma unroll
  for (int off = 32; off > 0; off >>= 1) tsum += __shfl_down(tsum, off);
  if (lane == 0) red[w] = tsum;
  __syncthreads();
  if (tid == 0) scal[72 + b] = red[0] + red[1] + red[2] + red[3];
}

// ---------------- K20: V = test - mean; U = V*B; q; block0: log_div ----------------
__global__ __launch_bounds__(256) void k_latent(const float* __restrict__ test, float* __restrict__ ws) {
  __shared__ unsigned short vh[16384];
  __shared__ float qs[128];
  int blk = blockIdx.x, tid = threadIdx.x;
  if (blk == 0 && tid == 0) {
    float* scal = ws + fSCAL;
    float trF2 = fmaxf(scal[72] + scal[73] + scal[74] + scal[75], 1e-30f);
    scal[0] = 0.5f * (128.0f * 1.8378770664093453f + 0.5f * logf(trF2));
  }
  const float* tb = test + blk * 128 * D;
  unsigned short* Vbf = (unsigned short*)(ws + fV);
  if (tid < 128) qs[tid] = 0.f;
  for (int idx = tid; idx < 16384; idx += 256) {
    int r = idx >> 7, c = idx & 127;
    float v = tb[idx] - ws[fMEAN + c];
    unsigned short h = f2bf(v);
    unsigned byte = ((unsigned)(r * 256 + c * 2)) ^ (((unsigned)(r & 7)) << 4);
    *(unsigned short*)((char*)vh + byte) = h;
    Vbf[blk * 16384 + idx] = h;
  }
  __syncthreads();
  int w = tid >> 6, lane = tid & 63;
  int wr = (w >> 1) * 64, wc = (w & 1) * 64;
  const unsigned short* Bbf = (const unsigned short*)(ws + fBBF);
  f32x4 acc[4][4] = {};
  for (int ks = 0; ks < 4; ks++) {
    int kb = ks * 32 + (lane >> 4) * 8;
    short8 af[4], bfv[4];
    #pragma unroll
    for (int mt = 0; mt < 4; mt++) {
      int r = wr + mt * 16 + (lane & 15);
      unsigned byte = ((unsigned)(r * 256 + kb * 2)) ^ (((unsigned)(r & 7)) << 4);
      af[mt] = *(short8*)((char*)vh + byte);
    }
    #pragma unroll
    for (int nt = 0; nt < 4; nt++) {
      int c = wc + nt * 16 + (lane & 15);
      bfv[nt] = *(const short8*)(Bbf + c * 128 + kb); // B symmetric
    }
    #pragma unroll
    for (int mt = 0; mt < 4; mt++)
      #pragma unroll
      for (int nt = 0; nt < 4; nt++)
        acc[mt][nt] = __builtin_amdgcn_mfma_f32_16x16x32_bf16(af[mt], bfv[nt], acc[mt][nt], 0, 0, 0);
  }
  unsigned short* Ubf = (unsigned short*)(ws + fU);
  #pragma unroll
  for (int mt = 0; mt < 4; mt++)
    #pragma unroll
    for (int nt = 0; nt < 4; nt++)
      #pragma unroll
      for (int r = 0; r < 4; r++) {
        int row = wr + mt * 16 + (lane >> 4) * 4 + r;
        int col = wc + nt * 16 + (lane & 15);
        Ubf[(blk * 128 + row) * 128 + col] = f2bf(acc[mt][nt][r]);
      }
  #pragma unroll
  for (int mt = 0; mt < 4; mt++)
    #pragma unroll
    for (int r = 0; r < 4; r++) {
      int row = wr + mt * 16 + (lane >> 4) * 4 + r;
      float p = 0.f;
      #pragma unroll
      for (int nt = 0; nt < 4; nt++) {
        int col = wc + nt * 16 + (lane & 15);
        unsigned byte = ((unsigned)(row * 256 + col * 2)) ^ (((unsigned)(row & 7)) << 4);
        p += bf2f(f2bf(acc[mt][nt][r])) * bf2f(*(unsigned short*)((char*)vh + byte));
      }
      p += __shfl_xor(p, 1, 16);
      p += __shfl_xor(p, 2, 16);
      p += __shfl_xor(p, 4, 16);
      p += __shfl_xor(p, 8, 16);
      if ((lane & 15) == 0) atomicAdd(&qs[row], p);  // exactly 2 adds/row
    }
  __syncthreads();
  if (tid < 128) ws[fQ + blk * 128 + tid] = qs[tid];
}

// ---------------- K21: out = 2 U V^T - q_i - q_j - log_div ----------------
__global__ __launch_bounds__(256) void k_pair(const float* __restrict__ ws, float* __restrict__ out) {
  __shared__ float qi[128];
  __shared__ float qj[128];
  __shared__ float sld;
  int bi = blockIdx.x, bj = blockIdx.y, tid = threadIdx.x;
  if (tid < 128) qi[tid] = ws[fQ + bi * 128 + tid];
  else qj[tid - 128] = ws[fQ + bj * 128 + (tid - 128)];
  if (tid == 0) sld = ws[fSCAL + 0];
  __syncthreads();
  int w = tid >> 6, lane = tid & 63;
  int wr = (w >> 1) * 64, wc = (w & 1) * 64;
  const unsigned short* Ubf = (const unsigned short*)(ws + fU);
  const unsigned short* Vbf = (const unsigned short*)(ws + fV);
  f32x4 acc[4][4] = {};
  for (int ks = 0; ks < 4; ks++) {
    int kb = ks * 32 + (lane >> 4) * 8;
    short8 af[4], bfv[4];
    #pragma unroll
    for (int mt = 0; mt < 4; mt++) {
      int r = bi * 128 + wr + mt * 16 + (lane & 15);
      af[mt] = *(const short8*)(Ubf + r * 128 + kb);
    }
    #pragma unroll
    for (int nt = 0; nt < 4; nt++) {
      int c = bj * 128 + wc + nt * 16 + (lane & 15);
      bfv[nt] = *(const short8*)(Vbf + c * 128 + kb);
    }
    #pragma unroll
    for (int mt = 0; mt < 4; mt++)
      #pragma unroll
      for (int nt = 0; nt < 4; nt++)
        acc[mt][nt] = __builtin_amdgcn_mfma_f32_16x16x32_bf16(af[mt], bfv[nt], acc[mt][nt], 0, 0, 0);
  }
  float ld = sld;
  #pragma unroll
  for (int mt = 0; mt < 4; mt++)
    #pragma unroll
    for (int nt = 0; nt < 4; nt++)
      #pragma unroll
      for (int r = 0; r < 4; r++) {
        int row = wr + mt * 16 + (lane >> 4) * 4 + r;
        int col = wc + nt * 16 + (lane & 15);
        float g = acc[mt][nt][r];
        out[(size_t)(bi * 128 + row) * MTEST + (bj * 128 + col)] =
          2.0f * g - qi[row] - qj[col] - ld;
      }
}

extern "C" void kernel_launch(void* const* d_in, const int* in_sizes, int n_in,
                              void* d_out, int out_size, void* d_ws, size_t ws_size,
                              hipStream_t stream) {
  (void)in_sizes; (void)n_in; (void)out_size; (void)ws_size;
  const float* X = (const float*)d_in[0];
  const float* test = (const float*)d_in[1];
  float* out = (float*)d_out;
  float* ws = (float*)d_ws;
  float* scal = ws + fSCAL;
  auto M = [&](int i) -> unsigned short* {
    return (unsigned short*)(ws + fMAT) + (size_t)i * 32768;
  };
  unsigned short* Bbf = (unsigned short*)(ws + fBBF);

  k_gt_partial<<<64, 256, 0, stream>>>(X, ws);
  k_reduce<<<64, 256, 0, stream>>>(ws);
  k_sb<<<4, 256, 0, stream>>>(ws);
  k_swfin<<<16, 256, 0, stream>>>(ws);
  // P powers
  k_mm<<<4, 256, 0, stream>>>(M(sP), M(sP), M(sP2), nullptr, 1.0f, nullptr, 0, 0, scal, -1, nullptr);
  k_mm2<<<8, 256, 0, stream>>>(M(sP2), M(sP), M(sP3), nullptr, 1.0f, 0, 0,
                               M(sP2), M(sP2), M(sP4), nullptr, 1.0f, 0, 0, scal, 60);
  k_p56z<<<4, 256, 0, stream>>>(ws);   // Z = S_wn^{-1/2}
  // M = Z SB Z; C2; C4 (+trM8)
  k_mm<<<4, 256, 0, stream>>>(M(sZ), M(sSB), M(sM1), nullptr, 1.0f, nullptr, 0, 0, scal, -1, nullptr);
  k_mm<<<4, 256, 0, stream>>>(M(sM1), M(sZ), M(sMm), nullptr, 1.0f, nullptr, 0, 0, scal, -1, nullptr);
  k_mm<<<4, 256, 0, stream>>>(M(sMm), M(sMm), M(sC2), nullptr, 1.0f, nullptr, 0, 0, scal, -1, nullptr);
  k_mm<<<4, 256, 0, stream>>>(M(sC2), M(sC2), M(sC4), nullptr, 1.0f, nullptr, 0, 0, scal, 68, nullptr);
  // Chebyshev basis in X
  k_xh_t2<<<16, 256, 0, stream>>>(ws);
  k_mm2<<<8, 256, 0, stream>>>(M(sXH), M(sT2), M(sT3), M(sXH), 2.0f, -1.0f, 0,
                               M(sT2), M(sT2), M(sT4), nullptr, 2.0f, 0, -1.0f, scal, -1);
  k_t5g<<<20, 256, 0, stream>>>(ws);   // T5 + G0..G4
  k_mm<<<4, 256, 0, stream>>>(M(sT5), M(sT5), M(sT10), nullptr, 2.0f, nullptr, 0, -1.0f, scal, -1, nullptr);
  k_mm2<<<8, 256, 0, stream>>>(M(sT10), M(sT5), M(sT15), M(sT5), 2.0f, -1.0f, 0,
                               M(sT10), M(sT10), M(sT20), nullptr, 2.0f, 0, -1.0f, scal, -1);
  k_bigF<<<4, 256, 0, stream>>>(ws);   // F + trF2
  // B = (63/64) inv_s Z F Z -> Bbf
  k_mm<<<4, 256, 0, stream>>>(M(sZ), M(sF), M(sA1), nullptr, 1.0f, nullptr, 0, 0, scal, -1, nullptr);
  k_mm<<<4, 256, 0, stream>>>(M(sA1), M(sZ), nullptr, nullptr, 1.0f, scal + 7, 0, 0, scal, -1, Bbf);
  k_latent<<<64, 256, 0, stream>>>(test, ws);
  k_pair<<<dim3(64, 64), 256, 0, stream>>>(ws, out);
}